// Round 7
// baseline (79843.579 us; speedup 1.0000x reference)
//
#include <hip/hip_runtime.h>
#include <stdint.h>

#define TB 512

// ---------------- JAX threefry2x32 (exact) ----------------
__device__ __forceinline__ uint32_t rotl32(uint32_t v, int s) {
    return (v << s) | (v >> (32 - s));
}

__device__ __forceinline__ void threefry2x32(uint32_t k0, uint32_t k1,
                                             uint32_t c0, uint32_t c1,
                                             uint32_t& o0, uint32_t& o1) {
    const uint32_t ks2 = k0 ^ k1 ^ 0x1BD11BDAu;
    uint32_t x0 = c0 + k0;
    uint32_t x1 = c1 + k1;
    x0 += x1; x1 = rotl32(x1, 13); x1 ^= x0;
    x0 += x1; x1 = rotl32(x1, 15); x1 ^= x0;
    x0 += x1; x1 = rotl32(x1, 26); x1 ^= x0;
    x0 += x1; x1 = rotl32(x1, 6);  x1 ^= x0;
    x0 += k1;  x1 += ks2 + 1u;
    x0 += x1; x1 = rotl32(x1, 17); x1 ^= x0;
    x0 += x1; x1 = rotl32(x1, 29); x1 ^= x0;
    x0 += x1; x1 = rotl32(x1, 16); x1 ^= x0;
    x0 += x1; x1 = rotl32(x1, 24); x1 ^= x0;
    x0 += ks2; x1 += k0 + 2u;
    x0 += x1; x1 = rotl32(x1, 13); x1 ^= x0;
    x0 += x1; x1 = rotl32(x1, 15); x1 ^= x0;
    x0 += x1; x1 = rotl32(x1, 26); x1 ^= x0;
    x0 += x1; x1 = rotl32(x1, 6);  x1 ^= x0;
    x0 += k0;  x1 += k1 + 3u;
    x0 += x1; x1 = rotl32(x1, 17); x1 ^= x0;
    x0 += x1; x1 = rotl32(x1, 29); x1 ^= x0;
    x0 += x1; x1 = rotl32(x1, 16); x1 ^= x0;
    x0 += x1; x1 = rotl32(x1, 24); x1 ^= x0;
    x0 += k1;  x1 += ks2 + 4u;
    x0 += x1; x1 = rotl32(x1, 13); x1 ^= x0;
    x0 += x1; x1 = rotl32(x1, 15); x1 ^= x0;
    x0 += x1; x1 = rotl32(x1, 26); x1 ^= x0;
    x0 += x1; x1 = rotl32(x1, 6);  x1 ^= x0;
    x0 += ks2; x1 += k0 + 5u;
    o0 = x0; o1 = x1;
}

__device__ __forceinline__ uint32_t jax_random_bits(uint32_t k0, uint32_t k1, uint32_t i) {
    uint32_t o0, o1;
    threefry2x32(k0, k1, 0u, i, o0, o1);
    return o0 ^ o1;
}

__device__ __forceinline__ float erfinv_f32(float x) {
    float w = -log1pf(-x * x);
    float p;
    if (w < 5.0f) {
        w = w - 2.5f;
        p = 2.81022636e-08f;
        p = fmaf(p, w, 3.43273939e-07f);
        p = fmaf(p, w, -3.5233877e-06f);
        p = fmaf(p, w, -4.39150654e-06f);
        p = fmaf(p, w, 0.00021858087f);
        p = fmaf(p, w, -0.00125372503f);
        p = fmaf(p, w, -0.00417768164f);
        p = fmaf(p, w, 0.246640727f);
        p = fmaf(p, w, 1.50140941f);
    } else {
        w = sqrtf(w) - 3.0f;
        p = -0.000200214257f;
        p = fmaf(p, w, 0.000100950558f);
        p = fmaf(p, w, 0.00134934322f);
        p = fmaf(p, w, -0.00367342844f);
        p = fmaf(p, w, 0.00573950773f);
        p = fmaf(p, w, -0.0076224613f);
        p = fmaf(p, w, 0.00943887047f);
        p = fmaf(p, w, 1.00167406f);
        p = fmaf(p, w, 2.83297682f);
    }
    return p * x;
}

__device__ __forceinline__ float normal_from_bits(uint32_t bits) {
    float f = __uint_as_float((bits >> 9) | 0x3F800000u) - 1.0f;
    float uu = fmaxf(-0.99999994f, fmaf(f, 2.0f, -0.99999994f));
    return 1.41421354f * erfinv_f32(uu);
}

__device__ __forceinline__ float gumbel_from_bits(uint32_t bits) {
    float f = __uint_as_float((bits >> 9) | 0x3F800000u) - 1.0f;
    float uu = fmaxf(1.17549435e-38f, f + 1.17549435e-38f);
    return -logf(-logf(uu));
}

__device__ __forceinline__ float jax_normal_elem(uint32_t k0, uint32_t k1, uint32_t i) {
    return normal_from_bits(jax_random_bits(k0, k1, i));
}

__device__ __forceinline__ void step_keys(int t, uint32_t& kx0, uint32_t& kx1,
                                          uint32_t& ky0, uint32_t& ky1,
                                          uint32_t& kc0, uint32_t& kc1) {
    uint32_t kk0, kk1;
    threefry2x32(0u, 42u, 0u, (uint32_t)t, kk0, kk1);
    threefry2x32(kk0, kk1, 0u, 0u, kx0, kx1);
    threefry2x32(kk0, kk1, 0u, 1u, ky0, ky1);
    threefry2x32(kk0, kk1, 0u, 2u, kc0, kc1);
}

// ---- ws layout ----
constexpr size_t CONS_OFF  = 0;        // 64 u32 (padded to 256)
constexpr size_t READY_OFF = 256;      // 64*256 u32 = 64 KB
constexpr size_t RING_OFF  = 65792;
constexpr int SLOT_FULL_F = 26688;     // XNZ 8192 | ONZ 2048 | GUM 16384 | UBP 64
constexpr int SLOT_GUM_F  = 16384;     // GUM only
constexpr int XNZ_O = 0, ONZ_O = 8192, GUM_O = 10240, UBP_O = 26624;

// ================= producer/consumer cooperative kernel =================
// blocks 0..63: consumers (one per batch, sequential chain).
// blocks 64+64k+b (k=0..2): producers for batch b, steps t%3==k.
__global__ __launch_bounds__(TB, 2) void smc_pc(
    const float* __restrict__ u, const float* __restrict__ y,
    const float* __restrict__ W_ih, const float* __restrict__ W_hh,
    const float* __restrict__ b_ih, const float* __restrict__ b_hh,
    const float* __restrict__ W1, const float* __restrict__ b1,
    const float* __restrict__ W2, const float* __restrict__ b2,
    const float* __restrict__ sigx, const float* __restrict__ sigy,
    float* __restrict__ out, float* __restrict__ ring,
    uint32_t* __restrict__ ready, uint32_t* __restrict__ cons,
    int R, int slotF, int mode) {
    const int bid = blockIdx.x;
    const int tid = threadIdx.x;
    const int b = bid & 63;

    if (bid >= 64) {
        // ---------------- producer ----------------
        const int k = (bid >> 6) - 1;   // 0..2
        for (int t = k; t < 256; t += 3) {
            if (t >= R) {
                if (tid == 0) {
                    while ((int)__hip_atomic_load(&cons[b], __ATOMIC_ACQUIRE,
                                                  __HIP_MEMORY_SCOPE_AGENT) < t - R + 1)
                        __builtin_amdgcn_s_sleep(8);
                }
                __syncthreads();
            }
            uint32_t kx0, kx1, ky0, ky1, kc0, kc1;
            step_keys(t, kx0, kx1, ky0, ky1, kc0, kc1);
            float* slot = ring + ((size_t)b * R + (size_t)(t % R)) * (size_t)slotF;
            if (mode == 0) {
                for (int it = tid; it < 8192; it += TB)
                    slot[XNZ_O + it] = jax_normal_elem(kx0, kx1, (uint32_t)(b * 8192 + it));
                for (int it = tid; it < 2048; it += TB)
                    slot[ONZ_O + it] = jax_normal_elem(ky0, ky1, (uint32_t)(b * 2048 + it));
                for (int it = tid; it < 16384; it += TB)
                    slot[GUM_O + it] = gumbel_from_bits(jax_random_bits(
                        kc0, kc1, ((uint32_t)(it >> 7) << 13) + (uint32_t)b * 128u + (uint32_t)(it & 127)));
                if (tid < 64) {  // ubp: same op order as r3 P1
                    const float* ut = u + ((size_t)t * 64 + b) * 64;
                    float s = 0.f;
                    #pragma unroll 4
                    for (int k2 = 0; k2 < 64; ++k2) s = fmaf(ut[k2], W_ih[k2 * 64 + tid], s);
                    slot[UBP_O + tid] = s + b_ih[tid];
                }
            } else {
                for (int it = tid; it < 16384; it += TB)
                    slot[it] = gumbel_from_bits(jax_random_bits(
                        kc0, kc1, ((uint32_t)(it >> 7) << 13) + (uint32_t)b * 128u + (uint32_t)(it & 127)));
            }
            __threadfence();
            __syncthreads();
            if (tid == 0)
                __hip_atomic_store(&ready[b * 256 + t], 1u, __ATOMIC_RELEASE,
                                   __HIP_MEMORY_SCOPE_AGENT);
        }
        return;
    }

    // ---------------- consumer: 512 threads, 4x4 tiles, full unroll ----------------
    __shared__ __align__(16) float xs[128][68];   // state; reused as h
    __shared__ __align__(16) float xn[128][68];   // post-noise state
    __shared__ __align__(16) float Wihs[64][68];  // mode!=0 only
    __shared__ __align__(16) float Whh[64][68];
    __shared__ __align__(16) float W1s[64][68];
    __shared__ __align__(16) float W2s[64][16];
    __shared__ float logw[128];
    __shared__ float ubp[64];                     // mode!=0 only
    __shared__ float bhhs[64], b1s[64], b2s[16], stdxv[64], stdyv[16], sigyv[16], ykv[16];
    __shared__ int   anc[128];

    for (int i = tid; i < 4096; i += TB) {
        const int r = i >> 6, c = i & 63;
        Whh[r][c] = W_hh[i];
        W1s[r][c] = W1[i];
    }
    if (mode != 0)
        for (int i = tid; i < 4096; i += TB) Wihs[i >> 6][i & 63] = W_ih[i];
    for (int i = tid; i < 1024; i += TB) W2s[i >> 4][i & 15] = W2[i];
    if (tid < 64) { bhhs[tid] = b_hh[tid]; b1s[tid] = b1[tid]; stdxv[tid] = sqrtf(sigx[tid]); }
    if (tid < 16) { b2s[tid] = b2[tid]; sigyv[tid] = sigy[tid]; stdyv[tid] = sqrtf(sigy[tid]); }

    {
        uint32_t xk0, xk1;
        threefry2x32(0u, 42u, 0u, 1048576u, xk0, xk1);
        for (int it = tid; it < 8192; it += TB) {
            const uint32_t idx = (uint32_t)b * 8192u + (uint32_t)it;
            xs[it >> 6][it & 63] = jax_normal_elem(xk0, xk1, idx);
        }
    }
    __syncthreads();

    for (int t = 0; t < 256; ++t) {
        // B1: wait for this step's precomputed noise (usually already set)
        if (tid == 0) {
            if (!__hip_atomic_load(&ready[b * 256 + t], __ATOMIC_RELAXED,
                                   __HIP_MEMORY_SCOPE_AGENT)) {
                while (!__hip_atomic_load(&ready[b * 256 + t], __ATOMIC_RELAXED,
                                          __HIP_MEMORY_SCOPE_AGENT))
                    __builtin_amdgcn_s_sleep(2);
            }
            (void)__hip_atomic_load(&ready[b * 256 + t], __ATOMIC_ACQUIRE,
                                    __HIP_MEMORY_SCOPE_AGENT);
        }
        __syncthreads();
        const float* slot = ring + ((size_t)b * R + (size_t)(t % R)) * (size_t)slotF;
        const int gumOff = (mode == 0) ? GUM_O : 0;

        uint32_t kx0 = 0, kx1 = 0, ky0 = 0, ky1 = 0;
        if (mode != 0) {
            uint32_t kc0d, kc1d;
            step_keys(t, kx0, kx1, ky0, ky1, kc0d, kc1d);
        }
        const float* yt = y + ((size_t)t * 64 + b) * 16;

        // P1 only in mode!=0 (ubp via LDS GEMM)
        if (mode != 0) {
            const float* ut = u + ((size_t)t * 64 + b) * 64;
            if (tid < 64) {
                float s = 0.f;
                #pragma unroll 4
                for (int k = 0; k < 64; ++k) s = fmaf(ut[k], Wihs[k][tid], s);
                ubp[tid] = s + b_ih[tid];
            }
            __syncthreads();
        }

        // P2: xn = tanh((ubp + xs@Whh) + bhh) + stdx*z  (4x4, full unroll)
        {
            if (tid < 16) ykv[tid] = yt[tid];   // consumed in fused P4 (post-barriers)
            const int n0 = (tid >> 4) << 2;
            const int d0 = (tid & 15) << 2;
            // prefetch ring operands before the GEMM (latency hides under FMA)
            float4 ub4, z[4];
            if (mode == 0) {
                ub4 = *(const float4*)(slot + UBP_O + d0);
                #pragma unroll
                for (int i = 0; i < 4; ++i)
                    z[i] = *(const float4*)&slot[XNZ_O + (n0 + i) * 64 + d0];
            } else {
                ub4 = *(const float4*)&ubp[d0];
            }
            float acc[4][4];
            #pragma unroll
            for (int i = 0; i < 4; ++i)
                #pragma unroll
                for (int j = 0; j < 4; ++j) acc[i][j] = 0.f;
            #pragma unroll
            for (int k4 = 0; k4 < 64; k4 += 4) {       // FULL unroll: imm offsets
                float4 a[4];
                #pragma unroll
                for (int i = 0; i < 4; ++i) a[i] = *(const float4*)&xs[n0 + i][k4];
                #pragma unroll
                for (int kk = 0; kk < 4; ++kk) {
                    const float4 wr = *(const float4*)&Whh[k4 + kk][d0];
                    #pragma unroll
                    for (int i = 0; i < 4; ++i) {
                        const float av = (&a[i].x)[kk];
                        acc[i][0] = fmaf(av, wr.x, acc[i][0]);
                        acc[i][1] = fmaf(av, wr.y, acc[i][1]);
                        acc[i][2] = fmaf(av, wr.z, acc[i][2]);
                        acc[i][3] = fmaf(av, wr.w, acc[i][3]);
                    }
                }
            }
            #pragma unroll
            for (int i = 0; i < 4; ++i) {
                const int n = n0 + i;
                float4 res;
                if (mode == 0) {
                    #pragma unroll
                    for (int j = 0; j < 4; ++j) {
                        const float v = tanhf(((&ub4.x)[j] + acc[i][j]) + bhhs[d0 + j]);
                        (&res.x)[j] = v + stdxv[d0 + j] * (&z[i].x)[j];
                    }
                } else {
                    #pragma unroll
                    for (int j = 0; j < 4; ++j) {
                        const int d = d0 + j;
                        const float v = tanhf(((&ub4.x)[j] + acc[i][j]) + bhhs[d]);
                        const float nz = jax_normal_elem(kx0, kx1, (uint32_t)(b * 8192 + n * 64 + d));
                        (&res.x)[j] = v + stdxv[d] * nz;
                    }
                }
                *(float4*)&xn[n][d0] = res;
            }
        }
        __syncthreads();

        // P3: h = relu(xn@W1 + b1) into xs  (4x4, full unroll)
        {
            const int n0 = (tid >> 4) << 2;
            const int d0 = (tid & 15) << 2;
            float acc[4][4];
            #pragma unroll
            for (int i = 0; i < 4; ++i)
                #pragma unroll
                for (int j = 0; j < 4; ++j) acc[i][j] = 0.f;
            #pragma unroll
            for (int k4 = 0; k4 < 64; k4 += 4) {
                float4 a[4];
                #pragma unroll
                for (int i = 0; i < 4; ++i) a[i] = *(const float4*)&xn[n0 + i][k4];
                #pragma unroll
                for (int kk = 0; kk < 4; ++kk) {
                    const float4 wr = *(const float4*)&W1s[k4 + kk][d0];
                    #pragma unroll
                    for (int i = 0; i < 4; ++i) {
                        const float av = (&a[i].x)[kk];
                        acc[i][0] = fmaf(av, wr.x, acc[i][0]);
                        acc[i][1] = fmaf(av, wr.y, acc[i][1]);
                        acc[i][2] = fmaf(av, wr.z, acc[i][2]);
                        acc[i][3] = fmaf(av, wr.w, acc[i][3]);
                    }
                }
            }
            #pragma unroll
            for (int i = 0; i < 4; ++i) {
                float4 res;
                #pragma unroll
                for (int j = 0; j < 4; ++j)
                    (&res.x)[j] = fmaxf(acc[i][j] + b1s[d0 + j], 0.0f);
                *(float4*)&xs[n0 + i][d0] = res;
            }
        }
        __syncthreads();

        // P4+P5 fused: y_hat = h@W2 + b2 + noise; out; logw via 4-lane tree.
        // Also prefetch this thread's 32 gumbels (consumed in P6 after barrier).
        float4 g[8];
        {
            const int n = tid >> 2;
            const int d0 = (tid & 3) << 2;
            const float* gp = slot + gumOff + n * 128 + (tid & 3) * 32;
            #pragma unroll
            for (int q = 0; q < 8; ++q) g[q] = ((const float4*)gp)[q];

            float4 acc = make_float4(0.f, 0.f, 0.f, 0.f);
            #pragma unroll
            for (int j4 = 0; j4 < 64; j4 += 4) {
                const float4 h4 = *(const float4*)&xs[n][j4];
                #pragma unroll
                for (int jj = 0; jj < 4; ++jj) {
                    const float4 wr = *(const float4*)&W2s[j4 + jj][d0];
                    const float hv = (&h4.x)[jj];
                    acc.x = fmaf(hv, wr.x, acc.x);
                    acc.y = fmaf(hv, wr.y, acc.y);
                    acc.z = fmaf(hv, wr.z, acc.z);
                    acc.w = fmaf(hv, wr.w, acc.w);
                }
            }
            float4 z4;
            if (mode == 0) {
                z4 = *(const float4*)&slot[ONZ_O + n * 16 + d0];
            } else {
                #pragma unroll
                for (int j = 0; j < 4; ++j)
                    (&z4.x)[j] = jax_normal_elem(ky0, ky1, (uint32_t)(b * 2048 + n * 16 + d0 + j));
            }
            float4 res;
            float s = 0.f;
            #pragma unroll
            for (int j = 0; j < 4; ++j) {       // ascending d within quad
                const int d = d0 + j;
                const float yhv = ((&acc.x)[j] + b2s[d]) + stdyv[d] * (&z4.x)[j];
                (&res.x)[j] = yhv;
                const float dd = yhv - ykv[d];
                s += (dd * dd) / sigyv[d];
            }
            *(float4*)&out[(((size_t)t * 64 + b) * 128 + n) * 16 + d0] = res;
            // 4-lane sequential-order combine: ((s0+s1)+s2)+s3
            const float s1 = __shfl_down(s, 1);
            const float s2 = __shfl_down(s, 2);
            const float s3 = __shfl_down(s, 3);
            if ((tid & 3) == 0) logw[n] = -0.5f * (((s + s1) + s2) + s3);
        }
        __syncthreads();

        // P6: categorical argmax (4 lanes/draw, 32 cats each, prefetched g)
        {
            const int p = tid >> 2;
            const int sub = tid & 3;
            float best = -3.402823466e+38f;
            int bi = 0;
            #pragma unroll
            for (int q = 0; q < 8; ++q) {
                #pragma unroll
                for (int j = 0; j < 4; ++j) {
                    const int n = (sub << 5) + (q << 2) + j;
                    const float v = logw[n] + (&g[q].x)[j];
                    if (v > best) { best = v; bi = n; }
                }
            }
            #pragma unroll
            for (int off = 1; off < 4; off <<= 1) {
                const float ov = __shfl_xor(best, off);
                const int   oi = __shfl_xor(bi, off);
                if (ov > best || (ov == best && oi < bi)) { best = ov; bi = oi; }
            }
            if (sub == 0) anc[p] = bi;
        }
        __syncthreads();

        // P7: resample
        for (int it = tid; it < 2048; it += TB) {
            const int n = it >> 4, qq = (it & 15) * 4;
            *(float4*)&xs[n][qq] = *(const float4*)&xn[anc[n]][qq];
        }
        __syncthreads();

        // publish progress (release orders the ring reads above)
        if (tid == 0)
            __hip_atomic_store(&cons[b], (uint32_t)(t + 1), __ATOMIC_RELEASE,
                               __HIP_MEMORY_SCOPE_AGENT);
    }
}

// ================= r3 monolithic fallback (ws too small) =================
__global__ __launch_bounds__(TB, 2) void smc_mono(
    const float* __restrict__ u, const float* __restrict__ y,
    const float* __restrict__ W_ih, const float* __restrict__ W_hh,
    const float* __restrict__ b_ih, const float* __restrict__ b_hh,
    const float* __restrict__ W1, const float* __restrict__ b1,
    const float* __restrict__ W2, const float* __restrict__ b2,
    const float* __restrict__ sigx, const float* __restrict__ sigy,
    float* __restrict__ out) {
    const int b = blockIdx.x;
    const int tid = threadIdx.x;

    __shared__ __align__(16) float xs[128][68];
    __shared__ __align__(16) float xn[128][68];
    __shared__ __align__(16) float Wihs[64][68];
    __shared__ __align__(16) float Whh[64][68];
    __shared__ __align__(16) float W1s[64][68];
    __shared__ __align__(16) float W2s[64][16];
    __shared__ __align__(16) float yh[128][16];
    __shared__ float logw[128];
    __shared__ float ubp[64];
    __shared__ float bhhs[64], b1s[64], b2s[16], stdxv[64], stdyv[16], sigyv[16], ykv[16];
    __shared__ int   anc[128];

    for (int i = tid; i < 4096; i += TB) {
        const int r = i >> 6, c = i & 63;
        Wihs[r][c] = W_ih[i];
        Whh[r][c]  = W_hh[i];
        W1s[r][c]  = W1[i];
    }
    for (int i = tid; i < 1024; i += TB) W2s[i >> 4][i & 15] = W2[i];
    if (tid < 64) { bhhs[tid] = b_hh[tid]; b1s[tid] = b1[tid]; stdxv[tid] = sqrtf(sigx[tid]); }
    if (tid < 16) { b2s[tid] = b2[tid]; sigyv[tid] = sigy[tid]; stdyv[tid] = sqrtf(sigy[tid]); }

    {
        uint32_t xk0, xk1;
        threefry2x32(0u, 42u, 0u, 1048576u, xk0, xk1);
        for (int it = tid; it < 8192; it += TB) {
            const uint32_t idx = (uint32_t)b * 8192u + (uint32_t)it;
            xs[it >> 6][it & 63] = jax_normal_elem(xk0, xk1, idx);
        }
    }
    __syncthreads();

    for (int t = 0; t < 256; ++t) {
        uint32_t kx0, kx1, ky0, ky1, kc0, kc1;
        step_keys(t, kx0, kx1, ky0, ky1, kc0, kc1);

        const float* ut = u + ((size_t)t * 64 + b) * 64;
        const float* yt = y + ((size_t)t * 64 + b) * 16;
        if (tid < 64) {
            float s = 0.f;
            #pragma unroll 4
            for (int k = 0; k < 64; ++k) s = fmaf(ut[k], Wihs[k][tid], s);
            ubp[tid] = s + b_ih[tid];
        }
        if (tid < 16) ykv[tid] = yt[tid];
        __syncthreads();

        {
            const int n0 = (tid >> 4) * 4;
            const int d0 = (tid & 15) * 4;
            float acc[4][4];
            #pragma unroll
            for (int i = 0; i < 4; ++i)
                #pragma unroll
                for (int j = 0; j < 4; ++j) acc[i][j] = 0.f;
            #pragma unroll 4
            for (int k4 = 0; k4 < 64; k4 += 4) {
                float4 a[4];
                #pragma unroll
                for (int i = 0; i < 4; ++i) a[i] = *(const float4*)&xs[n0 + i][k4];
                #pragma unroll
                for (int kk = 0; kk < 4; ++kk) {
                    const float4 wr = *(const float4*)&Whh[k4 + kk][d0];
                    #pragma unroll
                    for (int i = 0; i < 4; ++i) {
                        const float av = (&a[i].x)[kk];
                        acc[i][0] = fmaf(av, wr.x, acc[i][0]);
                        acc[i][1] = fmaf(av, wr.y, acc[i][1]);
                        acc[i][2] = fmaf(av, wr.z, acc[i][2]);
                        acc[i][3] = fmaf(av, wr.w, acc[i][3]);
                    }
                }
            }
            #pragma unroll
            for (int i = 0; i < 4; ++i) {
                const int n = n0 + i;
                float4 res;
                #pragma unroll
                for (int j = 0; j < 4; ++j) {
                    const int d = d0 + j;
                    (&res.x)[j] = tanhf((ubp[d] + acc[i][j]) + bhhs[d]);
                }
                *(float4*)&xn[n][d0] = res;
            }
            #pragma unroll
            for (int i = 0; i < 4; ++i) {
                const int n = n0 + i;
                float4 v = *(const float4*)&xn[n][d0];
                #pragma unroll
                for (int j = 0; j < 4; ++j) {
                    const int d = d0 + j;
                    const uint32_t idx = (uint32_t)(b * 8192 + n * 64 + d);
                    (&v.x)[j] = (&v.x)[j] + stdxv[d] * jax_normal_elem(kx0, kx1, idx);
                }
                *(float4*)&xn[n][d0] = v;
            }
        }
        __syncthreads();

        {
            const int n0 = (tid >> 4) * 4;
            const int d0 = (tid & 15) * 4;
            float acc[4][4];
            #pragma unroll
            for (int i = 0; i < 4; ++i)
                #pragma unroll
                for (int j = 0; j < 4; ++j) acc[i][j] = 0.f;
            #pragma unroll 4
            for (int k4 = 0; k4 < 64; k4 += 4) {
                float4 a[4];
                #pragma unroll
                for (int i = 0; i < 4; ++i) a[i] = *(const float4*)&xn[n0 + i][k4];
                #pragma unroll
                for (int kk = 0; kk < 4; ++kk) {
                    const float4 wr = *(const float4*)&W1s[k4 + kk][d0];
                    #pragma unroll
                    for (int i = 0; i < 4; ++i) {
                        const float av = (&a[i].x)[kk];
                        acc[i][0] = fmaf(av, wr.x, acc[i][0]);
                        acc[i][1] = fmaf(av, wr.y, acc[i][1]);
                        acc[i][2] = fmaf(av, wr.z, acc[i][2]);
                        acc[i][3] = fmaf(av, wr.w, acc[i][3]);
                    }
                }
            }
            #pragma unroll
            for (int i = 0; i < 4; ++i) {
                float4 res;
                #pragma unroll
                for (int j = 0; j < 4; ++j)
                    (&res.x)[j] = fmaxf(acc[i][j] + b1s[d0 + j], 0.0f);
                *(float4*)&xs[n0 + i][d0] = res;
            }
        }
        __syncthreads();

        {
            const int n = tid >> 2;
            const int d0 = (tid & 3) * 4;
            float4 acc = make_float4(0.f, 0.f, 0.f, 0.f);
            #pragma unroll 4
            for (int j4 = 0; j4 < 64; j4 += 4) {
                const float4 h4 = *(const float4*)&xs[n][j4];
                #pragma unroll
                for (int jj = 0; jj < 4; ++jj) {
                    const float4 wr = *(const float4*)&W2s[j4 + jj][d0];
                    const float hv = (&h4.x)[jj];
                    acc.x = fmaf(hv, wr.x, acc.x);
                    acc.y = fmaf(hv, wr.y, acc.y);
                    acc.z = fmaf(hv, wr.z, acc.z);
                    acc.w = fmaf(hv, wr.w, acc.w);
                }
            }
            float4 res;
            #pragma unroll
            for (int j = 0; j < 4; ++j) {
                const int d = d0 + j;
                const float v = (&acc.x)[j] + b2s[d];
                const float nz = jax_normal_elem(ky0, ky1, (uint32_t)(b * 2048 + n * 16 + d));
                const float yhv = v + stdyv[d] * nz;
                yh[n][d] = yhv;
                (&res.x)[j] = yhv;
            }
            *(float4*)&out[(((size_t)t * 64 + b) * 128 + n) * 16 + d0] = res;
        }
        __syncthreads();

        if (tid < 128) {
            float s = 0.f;
            for (int d = 0; d < 16; ++d) {
                const float dd = yh[tid][d] - ykv[d];
                s += (dd * dd) / sigyv[d];
            }
            logw[tid] = -0.5f * s;
        }
        __syncthreads();

        {
            const int p = tid >> 2;
            const int sub = tid & 3;
            float best = -3.402823466e+38f;
            int bi = 0;
            const uint32_t base_idx = (uint32_t)p * 8192u + (uint32_t)b * 128u;
            for (int m = 0; m < 32; ++m) {
                const int n = (sub << 5) + m;
                const float v = logw[n] + gumbel_from_bits(jax_random_bits(kc0, kc1, base_idx + (uint32_t)n));
                if (v > best) { best = v; bi = n; }
            }
            #pragma unroll
            for (int off = 1; off < 4; off <<= 1) {
                const float ov = __shfl_xor(best, off);
                const int   oi = __shfl_xor(bi, off);
                if (ov > best || (ov == best && oi < bi)) { best = ov; bi = oi; }
            }
            if (sub == 0) anc[p] = bi;
        }
        __syncthreads();

        for (int it = tid; it < 2048; it += TB) {
            const int n = it >> 4, qq = (it & 15) * 4;
            *(float4*)&xs[n][qq] = *(const float4*)&xn[anc[n]][qq];
        }
        __syncthreads();
    }
}

extern "C" void kernel_launch(void* const* d_in, const int* in_sizes, int n_in,
                              void* d_out, int out_size, void* d_ws, size_t ws_size,
                              hipStream_t stream) {
    const float* u    = (const float*)d_in[0];
    const float* y    = (const float*)d_in[1];
    const float* W_ih = (const float*)d_in[2];
    const float* W_hh = (const float*)d_in[3];
    const float* b_ih = (const float*)d_in[4];
    const float* b_hh = (const float*)d_in[5];
    const float* W1   = (const float*)d_in[6];
    const float* b1   = (const float*)d_in[7];
    const float* W2   = (const float*)d_in[8];
    const float* b2   = (const float*)d_in[9];
    const float* sigx = (const float*)d_in[10];
    const float* sigy = (const float*)d_in[11];
    float* out = (float*)d_out;

    const size_t needF3 = RING_OFF + (size_t)64 * 3 * SLOT_FULL_F * 4;
    const size_t needF2 = RING_OFF + (size_t)64 * 2 * SLOT_FULL_F * 4;
    const size_t needG2 = RING_OFF + (size_t)64 * 2 * SLOT_GUM_F * 4;
    int mode = -1, R = 0, slotF = 0;
    if (ws_size >= needF3)      { mode = 0; R = 3; slotF = SLOT_FULL_F; }
    else if (ws_size >= needF2) { mode = 0; R = 2; slotF = SLOT_FULL_F; }
    else if (ws_size >= needG2) { mode = 1; R = 2; slotF = SLOT_GUM_F; }

    if (mode >= 0) {
        uint32_t* cons  = (uint32_t*)((char*)d_ws + CONS_OFF);
        uint32_t* ready = (uint32_t*)((char*)d_ws + READY_OFF);
        float*    ring  = (float*)((char*)d_ws + RING_OFF);
        hipMemsetAsync(d_ws, 0, RING_OFF, stream);
        void* args[] = {
            (void*)&u, (void*)&y, (void*)&W_ih, (void*)&W_hh, (void*)&b_ih,
            (void*)&b_hh, (void*)&W1, (void*)&b1, (void*)&W2, (void*)&b2,
            (void*)&sigx, (void*)&sigy, (void*)&out, (void*)&ring,
            (void*)&ready, (void*)&cons, (void*)&R, (void*)&slotF, (void*)&mode};
        hipLaunchCooperativeKernel((const void*)smc_pc, dim3(256), dim3(TB),
                                   args, 0, stream);
    } else {
        hipLaunchKernelGGL(smc_mono, dim3(64), dim3(TB), 0, stream,
                           u, y, W_ih, W_hh, b_ih, b_hh, W1, b1, W2, b2, sigx, sigy, out);
    }
}

// Round 8
// 7943.611 us; speedup vs baseline: 10.0513x; 10.0513x over previous
//
#include <hip/hip_runtime.h>
#include <stdint.h>

#define TB 512

// ---------------- JAX threefry2x32 (exact) ----------------
__device__ __forceinline__ uint32_t rotl32(uint32_t v, int s) {
    return (v << s) | (v >> (32 - s));
}

__device__ __forceinline__ void threefry2x32(uint32_t k0, uint32_t k1,
                                             uint32_t c0, uint32_t c1,
                                             uint32_t& o0, uint32_t& o1) {
    const uint32_t ks2 = k0 ^ k1 ^ 0x1BD11BDAu;
    uint32_t x0 = c0 + k0;
    uint32_t x1 = c1 + k1;
    x0 += x1; x1 = rotl32(x1, 13); x1 ^= x0;
    x0 += x1; x1 = rotl32(x1, 15); x1 ^= x0;
    x0 += x1; x1 = rotl32(x1, 26); x1 ^= x0;
    x0 += x1; x1 = rotl32(x1, 6);  x1 ^= x0;
    x0 += k1;  x1 += ks2 + 1u;
    x0 += x1; x1 = rotl32(x1, 17); x1 ^= x0;
    x0 += x1; x1 = rotl32(x1, 29); x1 ^= x0;
    x0 += x1; x1 = rotl32(x1, 16); x1 ^= x0;
    x0 += x1; x1 = rotl32(x1, 24); x1 ^= x0;
    x0 += ks2; x1 += k0 + 2u;
    x0 += x1; x1 = rotl32(x1, 13); x1 ^= x0;
    x0 += x1; x1 = rotl32(x1, 15); x1 ^= x0;
    x0 += x1; x1 = rotl32(x1, 26); x1 ^= x0;
    x0 += x1; x1 = rotl32(x1, 6);  x1 ^= x0;
    x0 += k0;  x1 += k1 + 3u;
    x0 += x1; x1 = rotl32(x1, 17); x1 ^= x0;
    x0 += x1; x1 = rotl32(x1, 29); x1 ^= x0;
    x0 += x1; x1 = rotl32(x1, 16); x1 ^= x0;
    x0 += x1; x1 = rotl32(x1, 24); x1 ^= x0;
    x0 += k1;  x1 += ks2 + 4u;
    x0 += x1; x1 = rotl32(x1, 13); x1 ^= x0;
    x0 += x1; x1 = rotl32(x1, 15); x1 ^= x0;
    x0 += x1; x1 = rotl32(x1, 26); x1 ^= x0;
    x0 += x1; x1 = rotl32(x1, 6);  x1 ^= x0;
    x0 += ks2; x1 += k0 + 5u;
    o0 = x0; o1 = x1;
}

__device__ __forceinline__ uint32_t jax_random_bits(uint32_t k0, uint32_t k1, uint32_t i) {
    uint32_t o0, o1;
    threefry2x32(k0, k1, 0u, i, o0, o1);
    return o0 ^ o1;
}

__device__ __forceinline__ float erfinv_f32(float x) {
    float w = -log1pf(-x * x);
    float p;
    if (w < 5.0f) {
        w = w - 2.5f;
        p = 2.81022636e-08f;
        p = fmaf(p, w, 3.43273939e-07f);
        p = fmaf(p, w, -3.5233877e-06f);
        p = fmaf(p, w, -4.39150654e-06f);
        p = fmaf(p, w, 0.00021858087f);
        p = fmaf(p, w, -0.00125372503f);
        p = fmaf(p, w, -0.00417768164f);
        p = fmaf(p, w, 0.246640727f);
        p = fmaf(p, w, 1.50140941f);
    } else {
        w = sqrtf(w) - 3.0f;
        p = -0.000200214257f;
        p = fmaf(p, w, 0.000100950558f);
        p = fmaf(p, w, 0.00134934322f);
        p = fmaf(p, w, -0.00367342844f);
        p = fmaf(p, w, 0.00573950773f);
        p = fmaf(p, w, -0.0076224613f);
        p = fmaf(p, w, 0.00943887047f);
        p = fmaf(p, w, 1.00167406f);
        p = fmaf(p, w, 2.83297682f);
    }
    return p * x;
}

__device__ __forceinline__ float normal_from_bits(uint32_t bits) {
    float f = __uint_as_float((bits >> 9) | 0x3F800000u) - 1.0f;
    float uu = fmaxf(-0.99999994f, fmaf(f, 2.0f, -0.99999994f));
    return 1.41421354f * erfinv_f32(uu);
}

__device__ __forceinline__ float gumbel_from_bits(uint32_t bits) {
    float f = __uint_as_float((bits >> 9) | 0x3F800000u) - 1.0f;
    float uu = fmaxf(1.17549435e-38f, f + 1.17549435e-38f);
    return -logf(-logf(uu));
}

__device__ __forceinline__ float jax_normal_elem(uint32_t k0, uint32_t k1, uint32_t i) {
    return normal_from_bits(jax_random_bits(k0, k1, i));
}

__device__ __forceinline__ void step_keys(int t, uint32_t& kx0, uint32_t& kx1,
                                          uint32_t& ky0, uint32_t& ky1,
                                          uint32_t& kc0, uint32_t& kc1) {
    uint32_t kk0, kk1;
    threefry2x32(0u, 42u, 0u, (uint32_t)t, kk0, kk1);
    threefry2x32(kk0, kk1, 0u, 0u, kx0, kx1);
    threefry2x32(kk0, kk1, 0u, 1u, ky0, ky1);
    threefry2x32(kk0, kk1, 0u, 2u, kc0, kc1);
}

// ---- ws layout ----
constexpr size_t CONS_OFF  = 0;        // 64 u32 (padded to 256)
constexpr size_t READY_OFF = 256;      // 64*256 u32 = 64 KB
constexpr size_t RING_OFF  = 65792;
constexpr int SLOT_FULL_F = 26688;     // XNZ 8192 | ONZ 2048 | GUM 16384 | UBP 64
constexpr int XNZ_O = 0, ONZ_O = 8192, GUM_O = 10240, UBP_O = 26624;

// ================= producer/consumer cooperative kernel =================
// blocks 0..63: consumers (one per batch, sequential chain).
// blocks 64+64k+b (k=0..2): producers for batch b, steps t%3==k.
__global__ __launch_bounds__(TB, 2) void smc_pc(
    const float* __restrict__ u, const float* __restrict__ y,
    const float* __restrict__ W_ih, const float* __restrict__ W_hh,
    const float* __restrict__ b_ih, const float* __restrict__ b_hh,
    const float* __restrict__ W1, const float* __restrict__ b1,
    const float* __restrict__ W2, const float* __restrict__ b2,
    const float* __restrict__ sigx, const float* __restrict__ sigy,
    float* __restrict__ out, float* __restrict__ ring,
    uint32_t* __restrict__ ready, uint32_t* __restrict__ cons, int R) {
    const int bid = blockIdx.x;
    const int tid = threadIdx.x;
    const int b = bid & 63;

    if (bid >= 64) {
        // ---------------- producer ----------------
        const int k = (bid >> 6) - 1;   // 0..2
        for (int t = k; t < 256; t += 3) {
            if (t >= R) {
                if (tid == 0) {
                    while ((int)__hip_atomic_load(&cons[b], __ATOMIC_ACQUIRE,
                                                  __HIP_MEMORY_SCOPE_AGENT) < t - R + 1)
                        __builtin_amdgcn_s_sleep(8);
                }
                __syncthreads();
            }
            uint32_t kx0, kx1, ky0, ky1, kc0, kc1;
            step_keys(t, kx0, kx1, ky0, ky1, kc0, kc1);
            float* slot = ring + ((size_t)b * R + (size_t)(t % R)) * (size_t)SLOT_FULL_F;
            for (int it = tid; it < 8192; it += TB)
                slot[XNZ_O + it] = jax_normal_elem(kx0, kx1, (uint32_t)(b * 8192 + it));
            for (int it = tid; it < 2048; it += TB)
                slot[ONZ_O + it] = jax_normal_elem(ky0, ky1, (uint32_t)(b * 2048 + it));
            for (int it = tid; it < 16384; it += TB)
                slot[GUM_O + it] = gumbel_from_bits(jax_random_bits(
                    kc0, kc1, ((uint32_t)(it >> 7) << 13) + (uint32_t)b * 128u + (uint32_t)(it & 127)));
            if (tid < 64) {  // ubp: same op order as r3 P1
                const float* ut = u + ((size_t)t * 64 + b) * 64;
                float s = 0.f;
                #pragma unroll 4
                for (int k2 = 0; k2 < 64; ++k2) s = fmaf(ut[k2], W_ih[k2 * 64 + tid], s);
                slot[UBP_O + tid] = s + b_ih[tid];
            }
            __threadfence();
            __syncthreads();
            if (tid == 0)
                __hip_atomic_store(&ready[b * 256 + t], 1u, __ATOMIC_RELEASE,
                                   __HIP_MEMORY_SCOPE_AGENT);
        }
        return;
    }

    // ---------------- consumer: 512 threads, 4 phases, ping-pong state ----------------
    __shared__ __align__(16) float S0[128][68];   // ping-pong state / h buffer
    __shared__ __align__(16) float S1[128][68];
    __shared__ __align__(16) float Whh[64][68];
    __shared__ __align__(16) float W1s[64][68];
    __shared__ __align__(16) float W2s[64][16];
    __shared__ float logw[128];
    __shared__ float bhhs[64], b1s[64], b2s[16], stdxv[64], stdyv[16], sigyv[16], ykv[16];
    __shared__ int   anc[128];

    for (int i = tid; i < 4096; i += TB) {
        const int r = i >> 6, c = i & 63;
        Whh[r][c] = W_hh[i];
        W1s[r][c] = W1[i];
    }
    for (int i = tid; i < 1024; i += TB) W2s[i >> 4][i & 15] = W2[i];
    if (tid < 64) { bhhs[tid] = b_hh[tid]; b1s[tid] = b1[tid]; stdxv[tid] = sqrtf(sigx[tid]); }
    if (tid < 16) { b2s[tid] = b2[tid]; sigyv[tid] = sigy[tid]; stdyv[tid] = sqrtf(sigy[tid]); }
    if (tid < 128) anc[tid] = tid;                // identity ancestors for t=0

    {   // x0 -> S0
        uint32_t xk0, xk1;
        threefry2x32(0u, 42u, 0u, 1048576u, xk0, xk1);
        for (int it = tid; it < 8192; it += TB) {
            const uint32_t idx = (uint32_t)b * 8192u + (uint32_t)it;
            S0[it >> 6][it & 63] = jax_normal_elem(xk0, xk1, idx);
        }
    }
    __syncthreads();

    for (int t = 0; t < 256; ++t) {
        // B1: wait for this step's precomputed noise (usually already set)
        if (tid == 0) {
            if (!__hip_atomic_load(&ready[b * 256 + t], __ATOMIC_RELAXED,
                                   __HIP_MEMORY_SCOPE_AGENT)) {
                while (!__hip_atomic_load(&ready[b * 256 + t], __ATOMIC_RELAXED,
                                          __HIP_MEMORY_SCOPE_AGENT))
                    __builtin_amdgcn_s_sleep(2);
            }
            (void)__hip_atomic_load(&ready[b * 256 + t], __ATOMIC_ACQUIRE,
                                    __HIP_MEMORY_SCOPE_AGENT);
        }
        __syncthreads();
        const float* slot = ring + ((size_t)b * R + (size_t)(t % R)) * (size_t)SLOT_FULL_F;
        float (*Srd)[68] = (t & 1) ? S1 : S0;   // state (pre-resample rows, gathered via anc)
        float (*Swr)[68] = (t & 1) ? S0 : S1;   // new state xn
        const float* yt = y + ((size_t)t * 64 + b) * 16;

        // P2: xn = tanh((ubp + x@Whh) + bhh) + stdx*z   (4x4; x-rows = Srd[anc[n]])
        {
            if (tid < 16) ykv[tid] = yt[tid];   // consumed in P4 (post-barrier)
            const int n0 = (tid >> 4) << 2;
            const int d0 = (tid & 15) << 2;
            int ar[4];
            #pragma unroll
            for (int i = 0; i < 4; ++i) ar[i] = anc[n0 + i];
            // prefetch ring operands early (latency hides under FMA)
            float4 ub4 = *(const float4*)(slot + UBP_O + d0);
            float4 z[4];
            #pragma unroll
            for (int i = 0; i < 4; ++i)
                z[i] = *(const float4*)&slot[XNZ_O + (n0 + i) * 64 + d0];
            float acc[4][4];
            #pragma unroll
            for (int i = 0; i < 4; ++i)
                #pragma unroll
                for (int j = 0; j < 4; ++j) acc[i][j] = 0.f;
            #pragma unroll 4
            for (int k4 = 0; k4 < 64; k4 += 4) {
                float4 a[4];
                #pragma unroll
                for (int i = 0; i < 4; ++i) a[i] = *(const float4*)&Srd[ar[i]][k4];
                #pragma unroll
                for (int kk = 0; kk < 4; ++kk) {
                    const float4 wr = *(const float4*)&Whh[k4 + kk][d0];
                    #pragma unroll
                    for (int i = 0; i < 4; ++i) {
                        const float av = (&a[i].x)[kk];
                        acc[i][0] = fmaf(av, wr.x, acc[i][0]);
                        acc[i][1] = fmaf(av, wr.y, acc[i][1]);
                        acc[i][2] = fmaf(av, wr.z, acc[i][2]);
                        acc[i][3] = fmaf(av, wr.w, acc[i][3]);
                    }
                }
            }
            #pragma unroll
            for (int i = 0; i < 4; ++i) {
                float4 res;
                #pragma unroll
                for (int j = 0; j < 4; ++j) {
                    const float v = tanhf(((&ub4.x)[j] + acc[i][j]) + bhhs[d0 + j]);
                    (&res.x)[j] = v + stdxv[d0 + j] * (&z[i].x)[j];
                }
                *(float4*)&Swr[n0 + i][d0] = res;
            }
        }
        __syncthreads();

        // P3: h = relu(xn@W1 + b1) into Srd (old state rows are dead now)
        {
            const int n0 = (tid >> 4) << 2;
            const int d0 = (tid & 15) << 2;
            float acc[4][4];
            #pragma unroll
            for (int i = 0; i < 4; ++i)
                #pragma unroll
                for (int j = 0; j < 4; ++j) acc[i][j] = 0.f;
            #pragma unroll 4
            for (int k4 = 0; k4 < 64; k4 += 4) {
                float4 a[4];
                #pragma unroll
                for (int i = 0; i < 4; ++i) a[i] = *(const float4*)&Swr[n0 + i][k4];
                #pragma unroll
                for (int kk = 0; kk < 4; ++kk) {
                    const float4 wr = *(const float4*)&W1s[k4 + kk][d0];
                    #pragma unroll
                    for (int i = 0; i < 4; ++i) {
                        const float av = (&a[i].x)[kk];
                        acc[i][0] = fmaf(av, wr.x, acc[i][0]);
                        acc[i][1] = fmaf(av, wr.y, acc[i][1]);
                        acc[i][2] = fmaf(av, wr.z, acc[i][2]);
                        acc[i][3] = fmaf(av, wr.w, acc[i][3]);
                    }
                }
            }
            #pragma unroll
            for (int i = 0; i < 4; ++i) {
                float4 res;
                #pragma unroll
                for (int j = 0; j < 4; ++j)
                    (&res.x)[j] = fmaxf(acc[i][j] + b1s[d0 + j], 0.0f);
                *(float4*)&Srd[n0 + i][d0] = res;
            }
        }
        __syncthreads();

        // P4 (+fused logw): y_hat = h@W2 + b2 + noise; out; logw via 4-lane tree
        // (validated bit-stable in r7: absmax unchanged)
        {
            const int n = tid >> 2;
            const int d0 = (tid & 3) << 2;
            float4 acc = make_float4(0.f, 0.f, 0.f, 0.f);
            #pragma unroll 4
            for (int j4 = 0; j4 < 64; j4 += 4) {
                const float4 h4 = *(const float4*)&Srd[n][j4];
                #pragma unroll
                for (int jj = 0; jj < 4; ++jj) {
                    const float4 wr = *(const float4*)&W2s[j4 + jj][d0];
                    const float hv = (&h4.x)[jj];
                    acc.x = fmaf(hv, wr.x, acc.x);
                    acc.y = fmaf(hv, wr.y, acc.y);
                    acc.z = fmaf(hv, wr.z, acc.z);
                    acc.w = fmaf(hv, wr.w, acc.w);
                }
            }
            const float4 z4 = *(const float4*)&slot[ONZ_O + n * 16 + d0];
            float4 res;
            float s = 0.f;
            #pragma unroll
            for (int j = 0; j < 4; ++j) {       // ascending d within quad
                const int d = d0 + j;
                const float yhv = ((&acc.x)[j] + b2s[d]) + stdyv[d] * (&z4.x)[j];
                (&res.x)[j] = yhv;
                const float dd = yhv - ykv[d];
                s += (dd * dd) / sigyv[d];
            }
            *(float4*)&out[(((size_t)t * 64 + b) * 128 + n) * 16 + d0] = res;
            const float s1 = __shfl_down(s, 1);
            const float s2 = __shfl_down(s, 2);
            const float s3 = __shfl_down(s, 3);
            if ((tid & 3) == 0) logw[n] = -0.5f * (((s + s1) + s2) + s3);
        }
        __syncthreads();

        // P6: categorical argmax (4 lanes/draw, 32 cats each; gumbels from ring)
        {
            const int p = tid >> 2;
            const int sub = tid & 3;
            const float* gp = slot + GUM_O + p * 128 + (sub << 5);
            float best = -3.402823466e+38f;
            int bi = 0;
            for (int m4 = 0; m4 < 32; m4 += 4) {
                const float4 g4 = *(const float4*)&gp[m4];
                #pragma unroll
                for (int j = 0; j < 4; ++j) {
                    const int n = (sub << 5) + m4 + j;
                    const float v = logw[n] + (&g4.x)[j];
                    if (v > best) { best = v; bi = n; }
                }
            }
            #pragma unroll
            for (int off = 1; off < 4; off <<= 1) {
                const float ov = __shfl_xor(best, off);
                const int   oi = __shfl_xor(bi, off);
                if (ov > best || (ov == best && oi < bi)) { best = ov; bi = oi; }
            }
            if (sub == 0) anc[p] = bi;
        }
        __syncthreads();   // anc visible to next step's P2

        // publish progress (release orders the ring reads above)
        if (tid == 0)
            __hip_atomic_store(&cons[b], (uint32_t)(t + 1), __ATOMIC_RELEASE,
                               __HIP_MEMORY_SCOPE_AGENT);
    }
}

// ================= r3 monolithic fallback (ws too small) =================
__global__ __launch_bounds__(TB, 2) void smc_mono(
    const float* __restrict__ u, const float* __restrict__ y,
    const float* __restrict__ W_ih, const float* __restrict__ W_hh,
    const float* __restrict__ b_ih, const float* __restrict__ b_hh,
    const float* __restrict__ W1, const float* __restrict__ b1,
    const float* __restrict__ W2, const float* __restrict__ b2,
    const float* __restrict__ sigx, const float* __restrict__ sigy,
    float* __restrict__ out) {
    const int b = blockIdx.x;
    const int tid = threadIdx.x;

    __shared__ __align__(16) float xs[128][68];
    __shared__ __align__(16) float xn[128][68];
    __shared__ __align__(16) float Wihs[64][68];
    __shared__ __align__(16) float Whh[64][68];
    __shared__ __align__(16) float W1s[64][68];
    __shared__ __align__(16) float W2s[64][16];
    __shared__ __align__(16) float yh[128][16];
    __shared__ float logw[128];
    __shared__ float ubp[64];
    __shared__ float bhhs[64], b1s[64], b2s[16], stdxv[64], stdyv[16], sigyv[16], ykv[16];
    __shared__ int   anc[128];

    for (int i = tid; i < 4096; i += TB) {
        const int r = i >> 6, c = i & 63;
        Wihs[r][c] = W_ih[i];
        Whh[r][c]  = W_hh[i];
        W1s[r][c]  = W1[i];
    }
    for (int i = tid; i < 1024; i += TB) W2s[i >> 4][i & 15] = W2[i];
    if (tid < 64) { bhhs[tid] = b_hh[tid]; b1s[tid] = b1[tid]; stdxv[tid] = sqrtf(sigx[tid]); }
    if (tid < 16) { b2s[tid] = b2[tid]; sigyv[tid] = sigy[tid]; stdyv[tid] = sqrtf(sigy[tid]); }

    {
        uint32_t xk0, xk1;
        threefry2x32(0u, 42u, 0u, 1048576u, xk0, xk1);
        for (int it = tid; it < 8192; it += TB) {
            const uint32_t idx = (uint32_t)b * 8192u + (uint32_t)it;
            xs[it >> 6][it & 63] = jax_normal_elem(xk0, xk1, idx);
        }
    }
    __syncthreads();

    for (int t = 0; t < 256; ++t) {
        uint32_t kx0, kx1, ky0, ky1, kc0, kc1;
        step_keys(t, kx0, kx1, ky0, ky1, kc0, kc1);

        const float* ut = u + ((size_t)t * 64 + b) * 64;
        const float* yt = y + ((size_t)t * 64 + b) * 16;
        if (tid < 64) {
            float s = 0.f;
            #pragma unroll 4
            for (int k = 0; k < 64; ++k) s = fmaf(ut[k], Wihs[k][tid], s);
            ubp[tid] = s + b_ih[tid];
        }
        if (tid < 16) ykv[tid] = yt[tid];
        __syncthreads();

        {
            const int n0 = (tid >> 4) * 4;
            const int d0 = (tid & 15) * 4;
            float acc[4][4];
            #pragma unroll
            for (int i = 0; i < 4; ++i)
                #pragma unroll
                for (int j = 0; j < 4; ++j) acc[i][j] = 0.f;
            #pragma unroll 4
            for (int k4 = 0; k4 < 64; k4 += 4) {
                float4 a[4];
                #pragma unroll
                for (int i = 0; i < 4; ++i) a[i] = *(const float4*)&xs[n0 + i][k4];
                #pragma unroll
                for (int kk = 0; kk < 4; ++kk) {
                    const float4 wr = *(const float4*)&Whh[k4 + kk][d0];
                    #pragma unroll
                    for (int i = 0; i < 4; ++i) {
                        const float av = (&a[i].x)[kk];
                        acc[i][0] = fmaf(av, wr.x, acc[i][0]);
                        acc[i][1] = fmaf(av, wr.y, acc[i][1]);
                        acc[i][2] = fmaf(av, wr.z, acc[i][2]);
                        acc[i][3] = fmaf(av, wr.w, acc[i][3]);
                    }
                }
            }
            #pragma unroll
            for (int i = 0; i < 4; ++i) {
                const int n = n0 + i;
                float4 res;
                #pragma unroll
                for (int j = 0; j < 4; ++j) {
                    const int d = d0 + j;
                    (&res.x)[j] = tanhf((ubp[d] + acc[i][j]) + bhhs[d]);
                }
                *(float4*)&xn[n][d0] = res;
            }
            #pragma unroll
            for (int i = 0; i < 4; ++i) {
                const int n = n0 + i;
                float4 v = *(const float4*)&xn[n][d0];
                #pragma unroll
                for (int j = 0; j < 4; ++j) {
                    const int d = d0 + j;
                    const uint32_t idx = (uint32_t)(b * 8192 + n * 64 + d);
                    (&v.x)[j] = (&v.x)[j] + stdxv[d] * jax_normal_elem(kx0, kx1, idx);
                }
                *(float4*)&xn[n][d0] = v;
            }
        }
        __syncthreads();

        {
            const int n0 = (tid >> 4) * 4;
            const int d0 = (tid & 15) * 4;
            float acc[4][4];
            #pragma unroll
            for (int i = 0; i < 4; ++i)
                #pragma unroll
                for (int j = 0; j < 4; ++j) acc[i][j] = 0.f;
            #pragma unroll 4
            for (int k4 = 0; k4 < 64; k4 += 4) {
                float4 a[4];
                #pragma unroll
                for (int i = 0; i < 4; ++i) a[i] = *(const float4*)&xn[n0 + i][k4];
                #pragma unroll
                for (int kk = 0; kk < 4; ++kk) {
                    const float4 wr = *(const float4*)&W1s[k4 + kk][d0];
                    #pragma unroll
                    for (int i = 0; i < 4; ++i) {
                        const float av = (&a[i].x)[kk];
                        acc[i][0] = fmaf(av, wr.x, acc[i][0]);
                        acc[i][1] = fmaf(av, wr.y, acc[i][1]);
                        acc[i][2] = fmaf(av, wr.z, acc[i][2]);
                        acc[i][3] = fmaf(av, wr.w, acc[i][3]);
                    }
                }
            }
            #pragma unroll
            for (int i = 0; i < 4; ++i) {
                float4 res;
                #pragma unroll
                for (int j = 0; j < 4; ++j)
                    (&res.x)[j] = fmaxf(acc[i][j] + b1s[d0 + j], 0.0f);
                *(float4*)&xs[n0 + i][d0] = res;
            }
        }
        __syncthreads();

        {
            const int n = tid >> 2;
            const int d0 = (tid & 3) * 4;
            float4 acc = make_float4(0.f, 0.f, 0.f, 0.f);
            #pragma unroll 4
            for (int j4 = 0; j4 < 64; j4 += 4) {
                const float4 h4 = *(const float4*)&xs[n][j4];
                #pragma unroll
                for (int jj = 0; jj < 4; ++jj) {
                    const float4 wr = *(const float4*)&W2s[j4 + jj][d0];
                    const float hv = (&h4.x)[jj];
                    acc.x = fmaf(hv, wr.x, acc.x);
                    acc.y = fmaf(hv, wr.y, acc.y);
                    acc.z = fmaf(hv, wr.z, acc.z);
                    acc.w = fmaf(hv, wr.w, acc.w);
                }
            }
            float4 res;
            #pragma unroll
            for (int j = 0; j < 4; ++j) {
                const int d = d0 + j;
                const float v = (&acc.x)[j] + b2s[d];
                const float nz = jax_normal_elem(ky0, ky1, (uint32_t)(b * 2048 + n * 16 + d));
                const float yhv = v + stdyv[d] * nz;
                yh[n][d] = yhv;
                (&res.x)[j] = yhv;
            }
            *(float4*)&out[(((size_t)t * 64 + b) * 128 + n) * 16 + d0] = res;
        }
        __syncthreads();

        if (tid < 128) {
            float s = 0.f;
            for (int d = 0; d < 16; ++d) {
                const float dd = yh[tid][d] - ykv[d];
                s += (dd * dd) / sigyv[d];
            }
            logw[tid] = -0.5f * s;
        }
        __syncthreads();

        {
            const int p = tid >> 2;
            const int sub = tid & 3;
            float best = -3.402823466e+38f;
            int bi = 0;
            const uint32_t base_idx = (uint32_t)p * 8192u + (uint32_t)b * 128u;
            for (int m = 0; m < 32; ++m) {
                const int n = (sub << 5) + m;
                const float v = logw[n] + gumbel_from_bits(jax_random_bits(kc0, kc1, base_idx + (uint32_t)n));
                if (v > best) { best = v; bi = n; }
            }
            #pragma unroll
            for (int off = 1; off < 4; off <<= 1) {
                const float ov = __shfl_xor(best, off);
                const int   oi = __shfl_xor(bi, off);
                if (ov > best || (ov == best && oi < bi)) { best = ov; bi = oi; }
            }
            if (sub == 0) anc[p] = bi;
        }
        __syncthreads();

        for (int it = tid; it < 2048; it += TB) {
            const int n = it >> 4, qq = (it & 15) * 4;
            *(float4*)&xs[n][qq] = *(const float4*)&xn[anc[n]][qq];
        }
        __syncthreads();
    }
}

extern "C" void kernel_launch(void* const* d_in, const int* in_sizes, int n_in,
                              void* d_out, int out_size, void* d_ws, size_t ws_size,
                              hipStream_t stream) {
    const float* u    = (const float*)d_in[0];
    const float* y    = (const float*)d_in[1];
    const float* W_ih = (const float*)d_in[2];
    const float* W_hh = (const float*)d_in[3];
    const float* b_ih = (const float*)d_in[4];
    const float* b_hh = (const float*)d_in[5];
    const float* W1   = (const float*)d_in[6];
    const float* b1   = (const float*)d_in[7];
    const float* W2   = (const float*)d_in[8];
    const float* b2   = (const float*)d_in[9];
    const float* sigx = (const float*)d_in[10];
    const float* sigy = (const float*)d_in[11];
    float* out = (float*)d_out;

    const size_t needF3 = RING_OFF + (size_t)64 * 3 * SLOT_FULL_F * 4;
    const size_t needF2 = RING_OFF + (size_t)64 * 2 * SLOT_FULL_F * 4;
    int R = 0;
    if (ws_size >= needF3)      R = 3;
    else if (ws_size >= needF2) R = 2;

    if (R > 0) {
        uint32_t* cons  = (uint32_t*)((char*)d_ws + CONS_OFF);
        uint32_t* ready = (uint32_t*)((char*)d_ws + READY_OFF);
        float*    ring  = (float*)((char*)d_ws + RING_OFF);
        hipMemsetAsync(d_ws, 0, RING_OFF, stream);
        void* args[] = {
            (void*)&u, (void*)&y, (void*)&W_ih, (void*)&W_hh, (void*)&b_ih,
            (void*)&b_hh, (void*)&W1, (void*)&b1, (void*)&W2, (void*)&b2,
            (void*)&sigx, (void*)&sigy, (void*)&out, (void*)&ring,
            (void*)&ready, (void*)&cons, (void*)&R};
        hipLaunchCooperativeKernel((const void*)smc_pc, dim3(256), dim3(TB),
                                   args, 0, stream);
    } else {
        hipLaunchKernelGGL(smc_mono, dim3(64), dim3(TB), 0, stream,
                           u, y, W_ih, W_hh, b_ih, b_hh, W1, b1, W2, b2, sigx, sigy, out);
    }
}